// Round 12
// baseline (112.560 us; speedup 1.0000x reference)
//
#include <hip/hip_runtime.h>
#include <hip/hip_bf16.h>
#include <stdint.h>

#define B_ROWS 6144
#define N_ROWS 12288
#define DIM 256
#define NCLASS 512
#define MREP 3
#define ITILE 192                  // 4 waves * 48 rows; also j-tile height
#define NT (N_ROWS / ITILE)        // 64 tile grid -> 64*65/2 = 2080 blocks
#define NBLK (NT * (NT + 1) / 2)   // 2080
#define NITER 6                    // 192 j-rows / 32 per iteration
#define SCALE 14.426950408889634f  // log2(e)/0.1
#define PRESCALE 3.798282432f      // sqrt(SCALE); folded into embeddings
#define NCBLK NCLASS               // 512 classum blocks
#define WLCAP 128
#define PREPBLK (N_ROWS / 16)      // 768 prep blocks @1024 thr
#define FINBLK (N_ROWS / 256)      // 48
#define OFFS(t) ((t) * NT - (((t) * ((t)-1)) >> 1))

typedef float f32x4 __attribute__((ext_vector_type(4)));
typedef __bf16 bf16x8 __attribute__((ext_vector_type(8)));
typedef __bf16 bf16x4 __attribute__((ext_vector_type(4)));

// ---- workspace layout (bytes) ----
// ebf: swizzled bf16 of sqrt(SCALE)*normalized rows. Panel p = row>>4 (8 KB):
//   elem(row,d) = p*4096 + (d>>5)*512 + ((d>>3)&3)*128 + (row&15)*8 + (d&7)
// ps: [N_ROWS][NT] partial exp-sums; slot [row][c] written exactly once:
//   c>r by block (r,c) s_i; c<r by block (c,r) s_j; c==r by diag s_i.
#define WS_EBF  ((size_t)0)
#define WS_PS   ((size_t)(N_ROWS * DIM * 2))              // 6,291,456
#define WS_PSUM (WS_PS + (size_t)N_ROWS * NT * 4)         // + 3,145,728
#define WS_PART (WS_PSUM + (size_t)NCLASS * 4)            // + 2,048
#define WS_CNT  (WS_PART + (size_t)FINBLK * 4)            // + 192

__device__ inline void gload_lds16(const void* g, void* l) {
  __builtin_amdgcn_global_load_lds(
      (const __attribute__((address_space(1))) unsigned int*)g,
      (__attribute__((address_space(3))) unsigned int*)l, 16, 0, 0);
}

__device__ inline float block_sum_256(float v, float* sbuf) {
#pragma unroll
  for (int off = 32; off; off >>= 1) v += __shfl_down(v, off);
  const int lane = threadIdx.x & 63;
  const int w = threadIdx.x >> 6;
  __syncthreads();
  if (lane == 0) sbuf[w] = v;
  __syncthreads();
  return sbuf[0] + sbuf[1] + sbuf[2] + sbuf[3];
}

__device__ inline float block_sum_1024(float v, float* sbuf16) {
#pragma unroll
  for (int off = 32; off; off >>= 1) v += __shfl_down(v, off);
  const int lane = threadIdx.x & 63;
  const int w = threadIdx.x >> 6;
  __syncthreads();
  if (lane == 0) sbuf16[w] = v;
  __syncthreads();
  float t = 0.f;
#pragma unroll
  for (int i = 0; i < 16; ++i) t += sbuf16[i];
  return t;
}

// Kernel A (merged, 1024 threads): unchanged from R11 (proven).
__global__ __launch_bounds__(1024) void prep_classum_kernel(
    const float* __restrict__ o1, const float* __restrict__ o2,
    const long long* __restrict__ lab64, __bf16* __restrict__ ebf,
    float* __restrict__ psum) {
  __shared__ unsigned short wl[WLCAP];
  __shared__ int woff[16];
  __shared__ float spart[16][DIM];
  __shared__ float sbuf16[16];
  const int tid = threadIdx.x;
  const int lane = tid & 63;
  const int wv = tid >> 6;

  if (blockIdx.x >= NCBLK) {
    const int row = (blockIdx.x - NCBLK) * 16 + wv;
    const float* src = (row < B_ROWS) ? (o1 + (size_t)row * DIM)
                                      : (o2 + (size_t)(row - B_ROWS) * DIM);
    const float4 v = ((const float4*)src)[lane];
    float ss = v.x * v.x + v.y * v.y + v.z * v.z + v.w * v.w;
#pragma unroll
    for (int off = 1; off < 64; off <<= 1) ss += __shfl_xor(ss, off);
    const float rn = PRESCALE / fmaxf(sqrtf(ss), 1e-12f);
    bf16x4 h;
    h[0] = (__bf16)(v.x * rn); h[1] = (__bf16)(v.y * rn);
    h[2] = (__bf16)(v.z * rn); h[3] = (__bf16)(v.w * rn);
    const int p = row >> 4, r = row & 15;
    *(bf16x4*)(ebf + (size_t)p * 4096 + (lane >> 3) * 512 + ((lane >> 1) & 3) * 128
               + r * 8 + (lane & 1) * 4) = h;
    return;
  }

  const int c = blockIdx.x;
  unsigned long long bits = 0ull;
  int mycnt = 0;
#pragma unroll
  for (int it = 0; it < N_ROWS / 1024; ++it) {
    const int k = tid + it * 1024;
    const int lr = (k < B_ROWS) ? k : k - B_ROWS;
    if ((int)lab64[lr] == c) { bits |= (1ull << it); ++mycnt; }
  }
  int pre = mycnt;
#pragma unroll
  for (int off = 1; off < 64; off <<= 1) {
    const int o = __shfl_up(pre, off);
    if (lane >= off) pre += o;
  }
  if (lane == 63) woff[wv] = pre;
  __syncthreads();
  int wbase = 0, n = 0;
#pragma unroll
  for (int i = 0; i < 16; ++i) {
    const int wi = woff[i];
    wbase += (i < wv) ? wi : 0;
    n += wi;
  }
  if (n > WLCAP) n = WLCAP;
  int o = wbase + pre - mycnt;
#pragma unroll
  for (int it = 0; it < N_ROWS / 1024; ++it) {
    if ((bits >> it) & 1ull) {
      if (o < WLCAP) wl[o] = (unsigned short)(tid + it * 1024);
      ++o;
    }
  }
  __syncthreads();

  float4 a = {0.f, 0.f, 0.f, 0.f};
  for (int u = wv; u < n; u += 16) {
    const int row = wl[u];
    const float* src = (row < B_ROWS) ? (o1 + (size_t)row * DIM)
                                      : (o2 + (size_t)(row - B_ROWS) * DIM);
    const float4 v = ((const float4*)src)[lane];
    float ss = v.x * v.x + v.y * v.y + v.z * v.z + v.w * v.w;
#pragma unroll
    for (int off = 1; off < 64; off <<= 1) ss += __shfl_xor(ss, off);
    const float r = 1.0f / fmaxf(sqrtf(ss), 1e-12f);
    a.x += v.x * r; a.y += v.y * r; a.z += v.z * r; a.w += v.w * r;
  }
  *(float4*)&spart[wv][lane * 4] = a;
  __syncthreads();

  float s = 0.f;
  if (tid < DIM) {
#pragma unroll
    for (int i = 0; i < 16; ++i) s += spart[i][tid];
  }
  const float r2 = block_sum_1024(s * s, sbuf16);
  if (tid == 0) psum[c] = (n > 0) ? r2 / (float)n : 0.f;
}

// Kernel B: SYMMETRIC streaming exp-sums. Block = upper-tri tile pair
// (ti <= tj) of 192x192; computes exp2(SCALE*sim) once per pair and adds it
// to BOTH row-i sums (s_i, registers) and col-j sums (sjacc, LDS). Proven
// 3-buffer counted-vmcnt skeleton unchanged; NITER=6.
__global__ __launch_bounds__(256, 3) void lse_kernel(const __bf16* __restrict__ ebf,
                                                     float* __restrict__ ps) {
  __shared__ __align__(16) char smem[3 * 16384];
  __shared__ float sjacc[4][ITILE];   // per-wave col partials, 3 KB
  const int bid = blockIdx.x;
  // triangular (ti, tj) from bid
  int ti = (int)((2.0f * NT + 1.0f
                  - sqrtf((2.0f * NT + 1.0f) * (2.0f * NT + 1.0f) - 8.0f * (float)bid))
                 * 0.5f);
  if (ti < 0) ti = 0;
  if (ti > NT - 1) ti = NT - 1;
  while (ti < NT - 1 && OFFS(ti + 1) <= bid) ++ti;
  while (ti > 0 && OFFS(ti) > bid) --ti;
  const int tj = ti + (bid - OFFS(ti));
  const int i0 = ti * ITILE;
  const int j0 = tj * ITILE;
  const int tid = threadIdx.x;
  const int lane = tid & 63;
  const int w = tid >> 6;
  const char* const base = (const char*)ebf;

  // zero sjacc (before first barrier)
  for (int idx = tid; idx < 4 * ITILE; idx += 256) ((float*)sjacc)[idx] = 0.f;

  bf16x8 a[MREP][8];
  {
    const char* ap = base + (size_t)((i0 >> 4) + w * MREP) * 8192 + lane * 16;
#pragma unroll
    for (int m = 0; m < MREP; ++m)
#pragma unroll
      for (int kc = 0; kc < 8; ++kc)
        a[m][kc] = *(const bf16x8*)(ap + m * 8192 + kc * 1024);
  }

  float s[MREP][4];
#pragma unroll
  for (int m = 0; m < MREP; ++m)
#pragma unroll
    for (int r = 0; r < 4; ++r) s[m][r] = 0.0f;

  const char* gsrc0 = base + (size_t)(j0 >> 4) * 8192 + w * 1024 + lane * 16;

#pragma unroll
  for (int q = 0; q < 4; ++q)
    gload_lds16(gsrc0 + q * 4096, smem + w * 1024 + q * 4096);
#pragma unroll
  for (int q = 0; q < 4; ++q)
    gload_lds16(gsrc0 + 16384 + q * 4096, smem + 16384 + w * 1024 + q * 4096);
  __syncthreads();

  int bsel = 0;
  for (int t = 0; t < NITER; ++t) {
    if (t + 2 < NITER) {
      const char* gs = gsrc0 + (size_t)(t + 2) * 16384;
      char* ldst = smem + ((bsel + 2) % 3) * 16384 + w * 1024;
#pragma unroll
      for (int q = 0; q < 4; ++q) gload_lds16(gs + q * 4096, ldst + q * 4096);
    }

    const char* lb = smem + bsel * 16384 + lane * 16;
    f32x4 acc[MREP][2];
#pragma unroll
    for (int m = 0; m < MREP; ++m) {
      acc[m][0] = (f32x4){0.0f, 0.0f, 0.0f, 0.0f};
      acc[m][1] = (f32x4){0.0f, 0.0f, 0.0f, 0.0f};
    }
    __builtin_amdgcn_s_setprio(1);
#pragma unroll
    for (int kc = 0; kc < 8; ++kc) {
      const bf16x8 b0 = *(const bf16x8*)(lb + kc * 1024);
      const bf16x8 b1 = *(const bf16x8*)(lb + kc * 1024 + 8192);
#pragma unroll
      for (int m = 0; m < MREP; ++m) {
        acc[m][0] = __builtin_amdgcn_mfma_f32_16x16x32_bf16(a[m][kc], b0, acc[m][0], 0, 0, 0);
        acc[m][1] = __builtin_amdgcn_mfma_f32_16x16x32_bf16(a[m][kc], b1, acc[m][1], 0, 0, 0);
      }
    }
    __builtin_amdgcn_s_setprio(0);
    // epilogue: e = exp2(acc) once per pair; s_i in regs, col partials p0/p1
    float p0 = 0.f, p1 = 0.f;
#pragma unroll
    for (int m = 0; m < MREP; ++m)
#pragma unroll
      for (int r = 0; r < 4; ++r) {
        const float e0 = __builtin_amdgcn_exp2f(acc[m][0][r]);
        const float e1 = __builtin_amdgcn_exp2f(acc[m][1][r]);
        s[m][r] += e0 + e1;
        p0 += e0;
        p1 += e1;
      }
    // fold col partials across the 4 g-groups (rows) -> full 48-row col sums
    p0 += __shfl_xor(p0, 16); p0 += __shfl_xor(p0, 32);
    p1 += __shfl_xor(p1, 16); p1 += __shfl_xor(p1, 32);
    if (lane < 16) {
      sjacc[w][t * 32 + lane] += p0;
      sjacc[w][t * 32 + 16 + lane] += p1;
    }

    __builtin_amdgcn_sched_barrier(0);
    asm volatile("s_waitcnt lgkmcnt(0)" ::: "memory");
    if (t + 2 < NITER) {
      asm volatile("s_waitcnt vmcnt(4)" ::: "memory");
    } else {
      asm volatile("s_waitcnt vmcnt(0)" ::: "memory");
    }
    __builtin_amdgcn_sched_barrier(0);
    __builtin_amdgcn_s_barrier();
    __builtin_amdgcn_sched_barrier(0);

    bsel = (bsel + 1) % 3;
  }

  // s_i: merge across the 16 lanes sharing the same output rows
#pragma unroll
  for (int off = 1; off < 16; off <<= 1)
#pragma unroll
    for (int m = 0; m < MREP; ++m)
#pragma unroll
      for (int r = 0; r < 4; ++r)
        s[m][r] += __shfl_xor(s[m][r], off);

  if ((lane & 15) == 0) {
    const int g = lane >> 4;
#pragma unroll
    for (int m = 0; m < MREP; ++m)
#pragma unroll
      for (int r = 0; r < 4; ++r) {
        const int i = i0 + w * 48 + m * 16 + g * 4 + r;
        ps[(size_t)i * NT + tj] = s[m][r];
      }
  }

  // s_j: reduce wave partials, write (off-diagonal blocks only)
  __syncthreads();
  if (ti != tj) {
    for (int col = tid; col < ITILE; col += 256) {
      const float v = sjacc[0][col] + sjacc[1][col] + sjacc[2][col] + sjacc[3][col];
      ps[(size_t)(j0 + col) * NT + ti] = v;
    }
  }
}

// Kernel C (fused finish+mean): 48 blocks; last-arriving block reduces.
__global__ __launch_bounds__(256) void finishmean_kernel(
    const float* __restrict__ ps, const float* __restrict__ psum,
    float* __restrict__ partial, unsigned int* __restrict__ cnt,
    float* __restrict__ out) {
  __shared__ float sbuf[4];
  __shared__ int is_last;
  const int tid = threadIdx.x;
  const int row = blockIdx.x * 256 + tid;
  float sm = 0.f;
#pragma unroll
  for (int q = 0; q < NT / 4; ++q) {
    const float4 v = ((const float4*)(ps + (size_t)row * NT))[q];
    sm += v.x + v.y + v.z + v.w;
  }
  const float p = block_sum_256(logf(sm), sbuf);
  if (tid == 0) {
    partial[blockIdx.x] = p;
    __threadfence();
    const unsigned int old = atomicAdd(cnt, 1u);
    is_last = ((old % (unsigned)FINBLK) == (unsigned)(FINBLK - 1)) ? 1 : 0;
  }
  __syncthreads();
  if (!is_last) return;
  __threadfence();
  float v = (tid < FINBLK) ? atomicAdd(&partial[tid], 0.0f) : 0.0f;
  const float vs = block_sum_256(v, sbuf);
  const float qs = block_sum_256(psum[tid] + psum[tid + 256], sbuf);
  if (tid == 0)
    out[0] = vs * (1.0f / (float)N_ROWS) - qs * (10.0f / (float)N_ROWS);
}

extern "C" void kernel_launch(void* const* d_in, const int* in_sizes, int n_in,
                              void* d_out, int out_size, void* d_ws, size_t ws_size,
                              hipStream_t stream) {
  const float* o1 = (const float*)d_in[0];
  const float* o2 = (const float*)d_in[1];
  const long long* labels = (const long long*)d_in[2];
  char* ws = (char*)d_ws;
  __bf16* ebf = (__bf16*)(ws + WS_EBF);
  float* ps = (float*)(ws + WS_PS);
  float* psum = (float*)(ws + WS_PSUM);
  float* partial = (float*)(ws + WS_PART);
  unsigned int* cnt = (unsigned int*)(ws + WS_CNT);

  prep_classum_kernel<<<NCBLK + PREPBLK, 1024, 0, stream>>>(o1, o2, labels, ebf, psum);
  lse_kernel<<<NBLK, 256, 0, stream>>>(ebf, ps);
  finishmean_kernel<<<FINBLK, 256, 0, stream>>>(ps, psum, partial, cnt, (float*)d_out);
}